// Round 1
// baseline (1005.397 us; speedup 1.0000x reference)
//
#include <hip/hip_runtime.h>
#include <math.h>

#define PI_D 3.141592653589793238462643383279502884
#define PI_F 3.14159265358979323846f
#define SCALING_F (1.0f/12.0f)

// off[l] = sum_{j<l}(2j+1)^2
__constant__ int c_OFF[17] = {0,1,10,35,84,165,286,455,680,969,1330,1771,2300,2925,3654,4495,5456};
// cumulative blocks for k_z: per l: (2l+1)*ceil((2l+1)/4)
__constant__ int c_ZOFF[17] = {0,1,4,14,28,55,88,140,200,285,380,506,644,819,1008,1240,1488};

__device__ __forceinline__ void s_to_lmn(int s, int& l, int& m, int& n) {
    int ll = 15;
    while (s < c_OFF[ll]) --ll;
    int r = s - c_OFF[ll];
    int d = 2*ll + 1;
    l = ll;
    m = r / d - ll;
    n = r % d - ll;
}

// thread 0 fills log-factorial + half-angle power tables (double for accuracy)
__device__ void build_tables(double beta, double* lf, double* cp, double* sp) {
    lf[0] = 0.0;
    for (int i = 1; i < 64; ++i) lf[i] = lf[i-1] + log((double)i);
    double cb = cos(beta*0.5), sb = sin(beta*0.5);
    cp[0] = 1.0; sp[0] = 1.0;
    for (int i = 1; i < 64; ++i) { cp[i] = cp[i-1]*cb; sp[i] = sp[i-1]*sb; }
}

__device__ double wigner_d_dev(int l, int m, int n,
                               const double* lf, const double* cp, const double* sp) {
    int kmin = m - n; if (kmin < 0) kmin = 0;
    int kmax = l + m; { int k2 = l - n; if (k2 < kmax) kmax = k2; }
    double pref = 0.5*(lf[l+m] + lf[l-m] + lf[l+n] + lf[l-n]);
    double acc = 0.0;
    for (int k = kmin; k <= kmax; ++k) {
        double lg = pref - (lf[k] + lf[l+m-k] + lf[l-n-k] + lf[n-m+k]);
        double t = exp(lg) * cp[2*l + m - n - 2*k] * sp[n - m + 2*k];
        acc += (k & 1) ? -t : t;
    }
    return acc;
}

// ---- Wigner tables ----
__global__ void __launch_bounds__(256) k_wigner_in(float* Wan) {
    __shared__ double lf[64], cp[64], sp[64];
    __shared__ double wq;
    int j = blockIdx.x; // 0..63
    if (threadIdx.x == 0) {
        double beta = PI_D * (2*j + 1) / 128.0;   // 4*B_IN = 128
        build_tables(beta, lf, cp, sp);
        double inner = 0.0;
        for (int k = 0; k < 32; ++k)
            inner += sin((double)(2*j+1)*(2*k+1)*PI_D/128.0) / (double)(2*k+1);
        wq = (2.0/32.0) * sin(PI_D*(2*j+1)/128.0) * inner / 4096.0; // /(2b)^2
    }
    __syncthreads();
    for (int s = threadIdx.x; s < 5456; s += 256) {
        int l, m, n; s_to_lmn(s, l, m, n);
        Wan[s*64 + j] = (float)(wigner_d_dev(l, m, n, lf, cp, sp) * wq);
    }
}

__global__ void __launch_bounds__(256) k_wigner_out(float* Wsy) {
    __shared__ double lf[64], cp[64], sp[64];
    int j = blockIdx.x; // 0..31
    if (threadIdx.x == 0) build_tables(PI_D*(2*j+1)/64.0, lf, cp, sp); // 4*B_OUT=64
    __syncthreads();
    for (int s = threadIdx.x; s < 5456; s += 256) {
        int l, m, n; s_to_lmn(s, l, m, n);
        Wsy[s*32 + j] = (float)(wigner_d_dev(l, m, n, lf, cp, sp) * (double)(2*l+1));
    }
}

__global__ void __launch_bounds__(256) k_wigner_grid(const float* ge, float2* D) {
    __shared__ double lf[64], cp[64], sp[64];
    __shared__ double alp, gam;
    int g = blockIdx.x; // 0..71
    if (threadIdx.x == 0) {
        build_tables((double)ge[g*3 + 1], lf, cp, sp);
        alp = (double)ge[g*3 + 0];
        gam = (double)ge[g*3 + 2];
    }
    __syncthreads();
    for (int s = threadIdx.x; s < 5456; s += 256) {
        int l, m, n; s_to_lmn(s, l, m, n);
        double dv = wigner_d_dev(l, m, n, lf, cp, sp);
        double th = m*alp + n*gam;
        double sn, cs; sincos(th, &sn, &cs);
        D[s*72 + g] = make_float2((float)(dv*cs), (float)(-dv*sn));
    }
}

// ---- yc[s][i][o] = SCALING * sum_g kernel[i][o][g] * D[s][g] ----
__global__ void __launch_bounds__(256) k_yc(const float* kern, const float2* D, float2* yc) {
    __shared__ float2 Ds[72];
    int s = blockIdx.x;
    for (int g = threadIdx.x; g < 72; g += 256) Ds[g] = D[s*72 + g];
    __syncthreads();
    for (int io = threadIdx.x; io < 512; io += 256) {
        const float* kp = kern + io*72;
        float ar = 0.f, ai = 0.f;
        for (int g = 0; g < 72; ++g) {
            float kv = kp[g];
            ar = fmaf(kv, Ds[g].x, ar);
            ai = fmaf(kv, Ds[g].y, ai);
        }
        yc[(size_t)s*512 + io] = make_float2(ar*SCALING_F, ai*SCALING_F);
    }
}

// ---- forward 2D partial DFT per (b,f,j): Fx[bf][j][mm 0..30][nn 0..15] ----
__global__ void __launch_bounds__(256) k_fft(const float* x, float2* Fx) {
    __shared__ float xs[64][65];
    __shared__ float2 T1s[64][17];
    __shared__ float2 tw[64];
    int blk = blockIdx.x;           // bf*64 + j
    int bf = blk >> 6, j = blk & 63;
    const float* xp = x + (size_t)bf*262144 + j*64;  // x[b,f,a,j,g]
    for (int t = threadIdx.x; t < 4096; t += 256) {
        int a = t >> 6, g = t & 63;
        xs[a][g] = xp[(size_t)a*4096 + g];
    }
    if (threadIdx.x < 64) {
        float sn, cs;
        sincosf(-2.0f*PI_F*(float)threadIdx.x/64.0f, &sn, &cs);
        tw[threadIdx.x] = make_float2(cs, sn);   // e^{-2pi i t/64}
    }
    __syncthreads();
    // stage 1: T1[a][n] = sum_g x[a][g] e^{-2pi i n g/64}, n = 0..15
    {
        int a  = threadIdx.x & 63;
        int nb = (threadIdx.x >> 6) * 4;   // wave-uniform
        float2 c0 = {0,0}, c1 = {0,0}, c2 = {0,0}, c3 = {0,0};
        int t0 = 0, t1 = 0, t2 = 0, t3 = 0;
        for (int g = 0; g < 64; ++g) {
            float xv = xs[a][g];
            float2 w;
            w = tw[t0]; c0.x = fmaf(xv, w.x, c0.x); c0.y = fmaf(xv, w.y, c0.y); t0 = (t0 + nb)     & 63;
            w = tw[t1]; c1.x = fmaf(xv, w.x, c1.x); c1.y = fmaf(xv, w.y, c1.y); t1 = (t1 + nb + 1) & 63;
            w = tw[t2]; c2.x = fmaf(xv, w.x, c2.x); c2.y = fmaf(xv, w.y, c2.y); t2 = (t2 + nb + 2) & 63;
            w = tw[t3]; c3.x = fmaf(xv, w.x, c3.x); c3.y = fmaf(xv, w.y, c3.y); t3 = (t3 + nb + 3) & 63;
        }
        T1s[a][nb]   = c0; T1s[a][nb+1] = c1;
        T1s[a][nb+2] = c2; T1s[a][nb+3] = c3;
    }
    __syncthreads();
    // stage 2: Fx[mm][nn] = sum_a T1[a][nn] e^{-2pi i m a/64}, m = mm-15
    float2* outp = Fx + (size_t)blk*496;
    for (int idx = threadIdx.x; idx < 496; idx += 256) {
        int mm = idx >> 4, nn = idx & 15;
        int mstep = (mm + 49) & 63;     // (mm-15) mod 64
        float2 acc = {0,0};
        int t = 0;
        for (int a = 0; a < 64; ++a) {
            float2 tv = T1s[a][nn];
            float2 w  = tw[t];
            acc.x += tv.x*w.x - tv.y*w.y;
            acc.y += tv.x*w.y + tv.y*w.x;
            t = (t + mstep) & 63;
        }
        outp[idx] = acc;
    }
}

// ---- xc[s][bf] = sum_j Wan[s][j] * F(m(s),n(s)); block = (bf, mm) ----
__global__ void __launch_bounds__(256) k_xc(const float2* Fx, const float* Wan, float2* xc) {
    __shared__ float2 Fsh[31][65];   // [n+15][j]
    int blk = blockIdx.x;            // bf*31 + mm
    int bf = blk / 31, mm = blk - bf*31;
    int m = mm - 15;
    const float2* fp = Fx + (size_t)bf * 64 * 496;
    for (int t = threadIdx.x; t < 1024; t += 256) {   // n >= 0 from slice mm
        int j = t >> 4, nn = t & 15;
        Fsh[nn + 15][j] = fp[j*496 + mm*16 + nn];
    }
    for (int t = threadIdx.x; t < 1024; t += 256) {   // n < 0: conj of slice 30-mm
        int j = t >> 4, nn = t & 15;
        if (nn > 0) {
            float2 v = fp[j*496 + (30 - mm)*16 + nn];
            Fsh[15 - nn][j] = make_float2(v.x, -v.y);
        }
    }
    __syncthreads();
    int am = m < 0 ? -m : m;
    // enumerate pairs (l >= am, |n| <= l); count = 256 - am*am <= 256
    int q = threadIdx.x;
    int l = am;
    while (l <= 15 && q >= 2*l + 1) { q -= 2*l + 1; ++l; }
    if (l <= 15) {
        int n = q - l;
        int d = 2*l + 1;
        int s = c_OFF[l] + (m + l)*d + (n + l);
        const float* wp = Wan + (size_t)s*64;
        const float2* frow = Fsh[n + 15];
        float ar = 0.f, ai = 0.f;
        for (int j2 = 0; j2 < 64; ++j2) {
            float w = wp[j2];
            ar = fmaf(w, frow[j2].x, ar);
            ai = fmaf(w, frow[j2].y, ai);
        }
        xc[(size_t)s*128 + bf] = make_float2(ar, ai);
    }
}

// ---- per-l block matmul: z[m,n,b,o] = sum_{k,i} xb[m,k,b,i] yb[k,n,i,o] ----
__global__ void __launch_bounds__(256) k_z(const float2* xc, const float2* yc, float2* zc) {
    __shared__ float2 xsh[31*128];  // [k][bf]
    __shared__ float2 ysh[4*512];   // [nrow][io]
    int blk = blockIdx.x;
    int l = 0;
    while (l < 15 && blk >= c_ZOFF[l+1]) ++l;
    int r = blk - c_ZOFF[l];
    int d = 2*l + 1;
    int ntc = (d + 3) >> 2;
    int mi = r / ntc;
    int nt = r - mi*ntc;
    int off = c_OFF[l];
    const float2* xp = xc + (size_t)(off + mi*d)*128;
    for (int t = threadIdx.x; t < d*128; t += 256) xsh[t] = xp[t];
    int b = threadIdx.x >> 5, o = threadIdx.x & 31;
    float2 a0 = {0,0}, a1 = {0,0}, a2 = {0,0}, a3 = {0,0};
    int n0 = nt * 4;
    for (int k = 0; k < d; ++k) {
        __syncthreads();
        const float2* yp = yc + (size_t)(off + k*d)*512;
        for (int t = threadIdx.x; t < 2048; t += 256) {
            int row = t >> 9;
            int nrow = n0 + row; if (nrow > d - 1) nrow = d - 1;   // clamp (dup, unused)
            ysh[t] = yp[(size_t)nrow*512 + (t & 511)];
        }
        __syncthreads();
        const float2* xr = xsh + k*128 + b*16;
        const float2* y0 = ysh + o;
        #pragma unroll 4
        for (int i = 0; i < 16; ++i) {
            float2 xv = xr[i];
            float2 yv;
            yv = y0[i*32];
            a0.x += xv.x*yv.x - xv.y*yv.y; a0.y += xv.x*yv.y + xv.y*yv.x;
            yv = y0[512 + i*32];
            a1.x += xv.x*yv.x - xv.y*yv.y; a1.y += xv.x*yv.y + xv.y*yv.x;
            yv = y0[1024 + i*32];
            a2.x += xv.x*yv.x - xv.y*yv.y; a2.y += xv.x*yv.y + xv.y*yv.x;
            yv = y0[1536 + i*32];
            a3.x += xv.x*yv.x - xv.y*yv.y; a3.y += xv.x*yv.y + xv.y*yv.x;
        }
    }
    int sbase = off + mi*d + n0;
    if (n0 + 0 < d) zc[(size_t)(sbase + 0)*256 + threadIdx.x] = a0;
    if (n0 + 1 < d) zc[(size_t)(sbase + 1)*256 + threadIdx.x] = a1;
    if (n0 + 2 < d) zc[(size_t)(sbase + 2)*256 + threadIdx.x] = a2;
    if (n0 + 3 < d) zc[(size_t)(sbase + 3)*256 + threadIdx.x] = a3;
}

// ---- Xc[mm][j][nn][bo] = sum_l Wsy[s(l)][j] * zc[s(l)][bo] ----
__global__ void __launch_bounds__(256) k_scatter(const float2* zc, const float* Wsy, float2* Xc) {
    __shared__ float2 zsh[16*256];
    __shared__ float  wsh[16][33];
    int blk = blockIdx.x;               // mmi*31 + nni
    int mmi = blk / 31, nni = blk - mmi*31;
    int m = mmi - 15, n = nni - 15;
    int am = m < 0 ? -m : m, an = n < 0 ? -n : n;
    int lmin = am > an ? am : an;
    int nl = 16 - lmin;
    for (int li = 0; li < nl; ++li) {
        int l = lmin + li;
        int s = c_OFF[l] + (m + l)*(2*l + 1) + (n + l);
        zsh[li*256 + threadIdx.x] = zc[(size_t)s*256 + threadIdx.x];
        if (threadIdx.x < 32) wsh[li][threadIdx.x] = Wsy[(size_t)s*32 + threadIdx.x];
    }
    __syncthreads();
    float2 acc[32];
    #pragma unroll
    for (int j = 0; j < 32; ++j) acc[j] = make_float2(0.f, 0.f);
    for (int li = 0; li < nl; ++li) {
        float2 zv = zsh[li*256 + threadIdx.x];
        #pragma unroll
        for (int j = 0; j < 32; ++j) {
            float w = wsh[li][j];
            acc[j].x = fmaf(w, zv.x, acc[j].x);
            acc[j].y = fmaf(w, zv.y, acc[j].y);
        }
    }
    size_t base = ((size_t)mmi*32*31 + nni)*256 + threadIdx.x;
    #pragma unroll
    for (int j = 0; j < 32; ++j)
        Xc[base + (size_t)j*31*256] = acc[j];
}

// ---- U[j][bo][mm][g] = sum_n Xc[mm][j][nn][bo] e^{+2pi i n g/32} ----
__global__ void __launch_bounds__(256) k_u(const float2* Xc, float2* U) {
    __shared__ float2 Xsh[31*256];
    __shared__ float2 tw[32];
    int blk = blockIdx.x;              // mmi*32 + j
    int mmi = blk >> 5, j = blk & 31;
    const float2* xp = Xc + ((size_t)mmi*32 + j)*31*256;
    for (int t = threadIdx.x; t < 31*256; t += 256) Xsh[t] = xp[t];
    if (threadIdx.x < 32) {
        float sn, cs;
        sincosf(2.0f*PI_F*(float)threadIdx.x/32.0f, &sn, &cs);
        tw[threadIdx.x] = make_float2(cs, sn);   // e^{+2pi i t/32}
    }
    __syncthreads();
    float2 acc[32];
    #pragma unroll
    for (int g = 0; g < 32; ++g) acc[g] = make_float2(0.f, 0.f);
    for (int nni = 0; nni < 31; ++nni) {
        float2 xv = Xsh[nni*256 + threadIdx.x];
        int step = (nni + 17) & 31;    // (nni-15) mod 32, wave-uniform
        int t = 0;
        #pragma unroll
        for (int g = 0; g < 32; ++g) {
            float2 w = tw[t];
            acc[g].x += xv.x*w.x - xv.y*w.y;
            acc[g].y += xv.x*w.y + xv.y*w.x;
            t = (t + step) & 31;
        }
    }
    float2* up = U + (((size_t)j*256 + threadIdx.x)*31 + mmi)*32;
    #pragma unroll
    for (int g = 0; g < 32; ++g) up[g] = acc[g];
}

// ---- out[b][o][a][j][g] = bias[o] + sum_m Re(U[j][bo][mm][g] e^{+2pi i m a/32}) ----
__global__ void __launch_bounds__(256) k_out(const float2* U, const float* bias, float* out) {
    __shared__ float2 Ush[992];       // [mm][g]
    __shared__ float2 tw[32];
    int blk = blockIdx.x;             // bo*32 + j
    int bo = blk >> 5, j = blk & 31;
    const float2* up = U + ((size_t)j*256 + bo)*992;
    for (int t = threadIdx.x; t < 992; t += 256) Ush[t] = up[t];
    if (threadIdx.x < 32) {
        float sn, cs;
        sincosf(2.0f*PI_F*(float)threadIdx.x/32.0f, &sn, &cs);
        tw[threadIdx.x] = make_float2(cs, sn);
    }
    __syncthreads();
    float bv = bias[bo & 31];
    int a  = threadIdx.x >> 3;         // 0..31
    int g0 = (threadIdx.x & 7) << 2;   // 0,4,...,28
    float ac0 = bv, ac1 = bv, ac2 = bv, ac3 = bv;
    for (int mmi = 0; mmi < 31; ++mmi) {
        int t = (((mmi + 17) & 31) * a) & 31;  // (m*a) mod 32
        float2 w = tw[t];
        const float2* ur = Ush + mmi*32 + g0;
        float2 u0 = ur[0], u1 = ur[1], u2 = ur[2], u3 = ur[3];
        ac0 += u0.x*w.x - u0.y*w.y;
        ac1 += u1.x*w.x - u1.y*w.y;
        ac2 += u2.x*w.x - u2.y*w.y;
        ac3 += u3.x*w.x - u3.y*w.y;
    }
    float4 res = make_float4(ac0, ac1, ac2, ac3);
    *(float4*)(out + (((size_t)bo*32 + a)*32 + j)*32 + g0) = res;
}

extern "C" void kernel_launch(void* const* d_in, const int* in_sizes, int n_in,
                              void* d_out, int out_size, void* d_ws, size_t ws_size,
                              hipStream_t stream) {
    const float* x    = (const float*)d_in[0];  // (8,16,64,64,64)
    const float* kern = (const float*)d_in[1];  // (16,32,72)
    const float* bias = (const float*)d_in[2];  // (32,)
    const float* ge   = (const float*)d_in[3];  // (72,3)
    float* out = (float*)d_out;                 // (8,32,32,32,32)
    char* ws = (char*)d_ws;

    // workspace layout (bytes); U overlays dead regions after k_scatter
    float2* Xc  = (float2*)(ws);                  // 31*32*31*256 f2 = 62,980,096
    float*  Wan = (float*) (ws +  62980096);      // 5456*64  f32  =  1,396,736
    float*  Wsy = (float*) (ws +  64376832);      // 5456*32  f32  =    698,368
    float2* D   = (float2*)(ws +  65075200);      // 5456*72  f2   =  3,142,656
    float2* yc  = (float2*)(ws +  68217856);      // 5456*512 f2   = 22,347,776
    float2* zc  = (float2*)(ws +  90565632);      // 5456*256 f2   = 11,173,888
    float2* Fx  = (float2*)(ws + 101739520);      // 8192*496 f2   = 32,505,856
    float2* xc  = (float2*)(ws + 134245376);      // 5456*128 f2   =  5,586,944  (end 139,832,320)
    float2* U   = (float2*)(ws +  62980096);      // 8192*992 f2   = 65,011,712 (overlays Wan..zc, all dead)

    k_wigner_in  <<<  64, 256, 0, stream>>>(Wan);
    k_wigner_out <<<  32, 256, 0, stream>>>(Wsy);
    k_wigner_grid<<<  72, 256, 0, stream>>>(ge, D);
    k_yc         <<<5456, 256, 0, stream>>>(kern, D, yc);
    k_fft        <<<8192, 256, 0, stream>>>(x, Fx);
    k_xc         <<<3968, 256, 0, stream>>>(Fx, Wan, xc);   // 128 bf * 31 mm
    k_z          <<<1488, 256, 0, stream>>>(xc, yc, zc);
    k_scatter    <<< 961, 256, 0, stream>>>(zc, Wsy, Xc);   // 31*31
    k_u          <<< 992, 256, 0, stream>>>(Xc, U);         // 31*32
    k_out        <<<8192, 256, 0, stream>>>(U, bias, out);  // 256 bo * 32 j
}

// Round 2
// 876.680 us; speedup vs baseline: 1.1468x; 1.1468x over previous
//
#include <hip/hip_runtime.h>
#include <math.h>

#define PI_D 3.141592653589793238462643383279502884
#define PI_F 3.14159265358979323846f
#define SCALING_F (1.0f/12.0f)

// off[l] = sum_{j<l}(2j+1)^2
__constant__ int c_OFF[17] = {0,1,10,35,84,165,286,455,680,969,1330,1771,2300,2925,3654,4495,5456};
// cumulative blocks for k_z: per l: ceil(d/2)*ceil(d/8)
__constant__ int c_Z3[17] = {0,1,3,6,10,20,32,46,62,89,119,152,188,240,296,356,420};

__device__ __forceinline__ void s_to_lmn(int s, int& l, int& m, int& n) {
    int ll = 15;
    while (s < c_OFF[ll]) --ll;
    int r = s - c_OFF[ll];
    int d = 2*ll + 1;
    l = ll;
    m = r / d - ll;
    n = r % d - ll;
}

// parallel table build: thread i (<64) fills entry i
__device__ __forceinline__ void build_tables_par(double beta, double* lf, double* cp, double* sp) {
    if (threadIdx.x < 64) {
        int i = threadIdx.x;
        lf[i] = lgamma((double)(i + 1));           // log(i!)
        double cb = cos(beta*0.5), sb = sin(beta*0.5);
        cp[i] = (i == 0) ? 1.0 : exp((double)i * log(cb));
        sp[i] = (i == 0) ? 1.0 : exp((double)i * log(sb));
    }
}

__device__ double wigner_d_dev(int l, int m, int n,
                               const double* lf, const double* cp, const double* sp) {
    int kmin = m - n; if (kmin < 0) kmin = 0;
    int kmax = l + m; { int k2 = l - n; if (k2 < kmax) kmax = k2; }
    double pref = 0.5*(lf[l+m] + lf[l-m] + lf[l+n] + lf[l-n]);
    double acc = 0.0;
    for (int k = kmin; k <= kmax; ++k) {
        double lg = pref - (lf[k] + lf[l+m-k] + lf[l-n-k] + lf[n-m+k]);
        double t = exp(lg) * cp[2*l + m - n - 2*k] * sp[n - m + 2*k];
        acc += (k & 1) ? -t : t;
    }
    return acc;
}

// ---- Wigner tables ----
__global__ void __launch_bounds__(256) k_wigner_in(float* Wan) {
    __shared__ double lf[64], cp[64], sp[64];
    __shared__ double tsum[32];
    __shared__ double wq;
    int j = blockIdx.x >> 2;        // 0..63
    int chunk = blockIdx.x & 3;
    double beta = PI_D * (2*j + 1) / 128.0;   // 4*B_IN = 128
    build_tables_par(beta, lf, cp, sp);
    if (threadIdx.x >= 64 && threadIdx.x < 96) {
        int k = threadIdx.x - 64;
        tsum[k] = sin((double)(2*j+1)*(2*k+1)*PI_D/128.0) / (double)(2*k+1);
    }
    __syncthreads();
    if (threadIdx.x == 0) {
        double inner = 0.0;
        for (int k = 0; k < 32; ++k) inner += tsum[k];
        wq = (2.0/32.0) * sin(PI_D*(2*j+1)/128.0) * inner / 4096.0; // /(2b)^2
    }
    __syncthreads();
    int s0 = chunk*1364, s1 = s0 + 1364; if (s1 > 5456) s1 = 5456;
    for (int s = s0 + threadIdx.x; s < s1; s += 256) {
        int l, m, n; s_to_lmn(s, l, m, n);
        Wan[s*64 + j] = (float)(wigner_d_dev(l, m, n, lf, cp, sp) * wq);
    }
}

__global__ void __launch_bounds__(256) k_wigner_out(float* Wsy) {
    __shared__ double lf[64], cp[64], sp[64];
    int j = blockIdx.x >> 2;        // 0..31
    int chunk = blockIdx.x & 3;
    build_tables_par(PI_D*(2*j+1)/64.0, lf, cp, sp); // 4*B_OUT=64
    __syncthreads();
    int s0 = chunk*1364, s1 = s0 + 1364; if (s1 > 5456) s1 = 5456;
    for (int s = s0 + threadIdx.x; s < s1; s += 256) {
        int l, m, n; s_to_lmn(s, l, m, n);
        Wsy[s*32 + j] = (float)(wigner_d_dev(l, m, n, lf, cp, sp) * (double)(2*l+1));
    }
}

__global__ void __launch_bounds__(256) k_wigner_grid(const float* ge, float2* D) {
    __shared__ double lf[64], cp[64], sp[64];
    int g = blockIdx.x >> 2;        // 0..71
    int chunk = blockIdx.x & 3;
    double beta = (double)ge[g*3 + 1];
    double alp  = (double)ge[g*3 + 0];
    double gam  = (double)ge[g*3 + 2];
    build_tables_par(beta, lf, cp, sp);
    __syncthreads();
    int s0 = chunk*1364, s1 = s0 + 1364; if (s1 > 5456) s1 = 5456;
    for (int s = s0 + threadIdx.x; s < s1; s += 256) {
        int l, m, n; s_to_lmn(s, l, m, n);
        double dv = wigner_d_dev(l, m, n, lf, cp, sp);
        double th = m*alp + n*gam;
        double sn, cs; sincos(th, &sn, &cs);
        D[s*72 + g] = make_float2((float)(dv*cs), (float)(-dv*sn));
    }
}

// ---- yc[s][i][o] = SCALING * sum_g kernel[i][o][g] * D[s][g] ----
__global__ void __launch_bounds__(256) k_yc(const float* kern, const float2* D, float2* yc) {
    __shared__ float2 Ds[72];
    int s = blockIdx.x;
    for (int g = threadIdx.x; g < 72; g += 256) Ds[g] = D[s*72 + g];
    __syncthreads();
    for (int io = threadIdx.x; io < 512; io += 256) {
        const float* kp = kern + io*72;
        float ar = 0.f, ai = 0.f;
        for (int g = 0; g < 72; ++g) {
            float kv = kp[g];
            ar = fmaf(kv, Ds[g].x, ar);
            ai = fmaf(kv, Ds[g].y, ai);
        }
        yc[(size_t)s*512 + io] = make_float2(ar*SCALING_F, ai*SCALING_F);
    }
}

// ---- forward 2D partial DFT per (b,f,j): Fx[bf][j][mm 0..30][nn 0..15] ----
// register-tiled: stage1 thread = 2a x 2n, stage2 thread = 2mm x 1nn
__global__ void __launch_bounds__(256) k_fft(const float* x, float2* Fx) {
    __shared__ float  xs[64][66];
    __shared__ float2 T1s[16][66];   // [nn][a] transposed for stage-2 contiguous a reads
    __shared__ float2 tw2[16][64];   // tw2[n][g] = e^{-2pi i n g/64}
    int blk = blockIdx.x;            // bf*64 + j
    int bf = blk >> 6, j = blk & 63;
    const float* xp = x + (size_t)bf*262144 + j*64;  // x[b,f,a,j,g]
    for (int t = threadIdx.x; t < 1024; t += 256) {
        int a = t >> 4, g4 = (t & 15) << 2;
        float4 v = *(const float4*)(xp + (size_t)a*4096 + g4);
        xs[a][g4] = v.x; xs[a][g4+1] = v.y; xs[a][g4+2] = v.z; xs[a][g4+3] = v.w;
    }
    for (int t = threadIdx.x; t < 1024; t += 256) {
        int n = t >> 6, g = t & 63;
        float sn, cs;
        sincosf(-2.0f*PI_F*(float)((n*g) & 63)/64.0f, &sn, &cs);
        tw2[n][g] = make_float2(cs, sn);
    }
    __syncthreads();
    // stage 1: T1[n][a] = sum_g x[a][g] tw2[n][g], n = 0..15
    {
        int ag = threadIdx.x & 31, ng = threadIdx.x >> 5;
        int a0 = ag*2, n0 = ng*2;
        float2 a00 = {0,0}, a01 = {0,0}, a10 = {0,0}, a11 = {0,0};
        for (int g0 = 0; g0 < 64; g0 += 4) {
            float  x0[4], x1[4]; float2 w0[4], w1[4];
            #pragma unroll
            for (int r = 0; r < 4; ++r) {
                x0[r] = xs[a0][g0+r];   x1[r] = xs[a0+1][g0+r];
                w0[r] = tw2[n0][g0+r];  w1[r] = tw2[n0+1][g0+r];
            }
            #pragma unroll
            for (int r = 0; r < 4; ++r) {
                a00.x = fmaf(x0[r], w0[r].x, a00.x); a00.y = fmaf(x0[r], w0[r].y, a00.y);
                a01.x = fmaf(x0[r], w1[r].x, a01.x); a01.y = fmaf(x0[r], w1[r].y, a01.y);
                a10.x = fmaf(x1[r], w0[r].x, a10.x); a10.y = fmaf(x1[r], w0[r].y, a10.y);
                a11.x = fmaf(x1[r], w1[r].x, a11.x); a11.y = fmaf(x1[r], w1[r].y, a11.y);
            }
        }
        T1s[n0  ][a0] = a00; T1s[n0+1][a0]   = a01;
        T1s[n0  ][a0+1] = a10; T1s[n0+1][a0+1] = a11;
    }
    __syncthreads();
    // stage 2: Fx[mm][nn] = sum_a T1[nn][a] e^{-2pi i (mm-15) a/64}
    {
        int nn = threadIdx.x & 15, mmg = threadIdx.x >> 4;
        int mm0 = mmg*2, mm1 = mm0 + 1;
        int am0 = mm0 >= 15 ? mm0 - 15 : 15 - mm0;
        int am1 = mm1 >= 15 ? mm1 - 15 : 15 - mm1;
        if (am1 > 15) am1 = 15;                 // pad slot mm=31, discarded
        float sg0 = mm0 >= 15 ? 1.f : -1.f;     // conj for negative m
        float sg1 = mm1 >= 15 ? 1.f : -1.f;
        float2 c0 = {0,0}, c1 = {0,0};
        for (int a0 = 0; a0 < 64; a0 += 4) {
            #pragma unroll
            for (int r = 0; r < 4; ++r) {
                float2 t1 = T1s[nn][a0+r];
                float2 wa = tw2[am0][a0+r];
                float2 wb = tw2[am1][a0+r];
                float way = wa.y*sg0, wby = wb.y*sg1;
                c0.x += t1.x*wa.x - t1.y*way;
                c0.y += t1.x*way + t1.y*wa.x;
                c1.x += t1.x*wb.x - t1.y*wby;
                c1.y += t1.x*wby + t1.y*wb.x;
            }
        }
        float2* outp = Fx + (size_t)blk*496;
        outp[mm0*16 + nn] = c0;
        if (mm1 < 31) outp[mm1*16 + nn] = c1;
    }
}

// ---- xc[s][bf] = sum_j Wan[s][j] * F(m(s),n(s)); block = (bf, mm) ----
__global__ void __launch_bounds__(256) k_xc(const float2* Fx, const float* Wan, float2* xc) {
    __shared__ float2 Fsh[31][65];   // [n+15][j]
    int blk = blockIdx.x;            // bf*31 + mm
    int bf = blk / 31, mm = blk - bf*31;
    int m = mm - 15;
    const float2* fp = Fx + (size_t)bf * 64 * 496;
    for (int t = threadIdx.x; t < 1024; t += 256) {   // n >= 0 from slice mm
        int j = t >> 4, nn = t & 15;
        Fsh[nn + 15][j] = fp[j*496 + mm*16 + nn];
    }
    for (int t = threadIdx.x; t < 1024; t += 256) {   // n < 0: conj of slice 30-mm
        int j = t >> 4, nn = t & 15;
        if (nn > 0) {
            float2 v = fp[j*496 + (30 - mm)*16 + nn];
            Fsh[15 - nn][j] = make_float2(v.x, -v.y);
        }
    }
    __syncthreads();
    int am = m < 0 ? -m : m;
    int q = threadIdx.x;
    int l = am;
    while (l <= 15 && q >= 2*l + 1) { q -= 2*l + 1; ++l; }
    if (l <= 15) {
        int n = q - l;
        int d = 2*l + 1;
        int s = c_OFF[l] + (m + l)*d + (n + l);
        const float* wp = Wan + (size_t)s*64;
        const float2* frow = Fsh[n + 15];
        float ar = 0.f, ai = 0.f;
        for (int j2 = 0; j2 < 64; ++j2) {
            float w = wp[j2];
            ar = fmaf(w, frow[j2].x, ar);
            ai = fmaf(w, frow[j2].y, ai);
        }
        xc[(size_t)s*128 + bf] = make_float2(ar, ai);
    }
}

// ---- per-l block matmul: z[m,n,b,o] = sum_{k,i} xb[m,k,b,i] yb[k,n,i,o] ----
// block = (l, m-pair, n-octet); thread = (o, 2b, 4n); per-k staging of x-row + transposed y-tile
__global__ void __launch_bounds__(256) k_z(const float2* xc, const float2* yc, float2* zc) {
    __shared__ float2 xsh[2*128];       // [mj][bf] for current k
    __shared__ float2 ysh[8*32*17];     // [nl][o][i] pad 17
    int blk = 419 - blockIdx.x;         // heavy l first
    int l = 0;
    while (l < 15 && blk >= c_Z3[l+1]) ++l;
    int r = blk - c_Z3[l];
    int d = 2*l + 1;
    int nqc = (d + 7) >> 3;
    int mp = r / nqc;
    int nq = r - mp*nqc;
    int off = c_OFF[l];
    int m0 = mp*2;
    int o   = threadIdx.x & 31;
    int bh  = (threadIdx.x >> 5) & 3;
    int nq2 = threadIdx.x >> 7;
    int nb  = nq*8 + nq2*4;
    float2 acc[2][2][4];
    #pragma unroll
    for (int mj = 0; mj < 2; ++mj)
        #pragma unroll
        for (int bj = 0; bj < 2; ++bj)
            #pragma unroll
            for (int nj = 0; nj < 4; ++nj) acc[mj][bj][nj] = make_float2(0.f, 0.f);

    for (int k = 0; k < d; ++k) {
        __syncthreads();
        {   // stage x rows for this k: 2 x 128
            int mj = threadIdx.x >> 7;
            int bfi = threadIdx.x & 127;
            int mrow = m0 + mj; if (mrow > d-1) mrow = d-1;
            xsh[threadIdx.x] = xc[(size_t)(off + mrow*d + k)*128 + bfi];
        }
        // stage y tile transposed: ysh[nl][o][i] = yb[k][nq*8+nl][i][o]
        #pragma unroll
        for (int rr = 0; rr < 16; ++rr) {
            int q = rr*256 + threadIdx.x;
            int nl = q >> 9, rem = q & 511, i = rem >> 5, o2 = rem & 31;
            int nrow = nq*8 + nl;
            float2 v = make_float2(0.f, 0.f);
            if (nrow < d) v = yc[(size_t)(off + k*d + nrow)*512 + i*32 + o2];
            ysh[(nl*32 + o2)*17 + i] = v;
        }
        __syncthreads();
        const float2* x0 = xsh       + (bh*2    )*16;
        const float2* x1 = xsh       + (bh*2 + 1)*16;
        const float2* x2 = xsh + 128 + (bh*2    )*16;
        const float2* x3 = xsh + 128 + (bh*2 + 1)*16;
        #pragma unroll 4
        for (int i = 0; i < 16; ++i) {
            float2 xv00 = x0[i], xv01 = x1[i], xv10 = x2[i], xv11 = x3[i];
            #pragma unroll
            for (int nj = 0; nj < 4; ++nj) {
                float2 yv = ysh[((nq2*4 + nj)*32 + o)*17 + i];
                acc[0][0][nj].x += xv00.x*yv.x - xv00.y*yv.y;
                acc[0][0][nj].y += xv00.x*yv.y + xv00.y*yv.x;
                acc[0][1][nj].x += xv01.x*yv.x - xv01.y*yv.y;
                acc[0][1][nj].y += xv01.x*yv.y + xv01.y*yv.x;
                acc[1][0][nj].x += xv10.x*yv.x - xv10.y*yv.y;
                acc[1][0][nj].y += xv10.x*yv.y + xv10.y*yv.x;
                acc[1][1][nj].x += xv11.x*yv.x - xv11.y*yv.y;
                acc[1][1][nj].y += xv11.x*yv.y + xv11.y*yv.x;
            }
        }
    }
    #pragma unroll
    for (int mj = 0; mj < 2; ++mj) {
        int mrow = m0 + mj;
        if (mrow >= d) continue;
        #pragma unroll
        for (int nj = 0; nj < 4; ++nj) {
            int n = nb + nj;
            if (n >= d) continue;
            size_t s = (size_t)(off + mrow*d + n);
            zc[s*256 + (bh*2    )*32 + o] = acc[mj][0][nj];
            zc[s*256 + (bh*2 + 1)*32 + o] = acc[mj][1][nj];
        }
    }
}

// ---- Xc[mm][j][nn][bo] = sum_l Wsy[s(l)][j] * zc[s(l)][bo] ----
__global__ void __launch_bounds__(256) k_scatter(const float2* zc, const float* Wsy, float2* Xc) {
    __shared__ float2 zsh[16*256];
    __shared__ float  wsh[16][33];
    int blk = blockIdx.x;               // mmi*31 + nni
    int mmi = blk / 31, nni = blk - mmi*31;
    int m = mmi - 15, n = nni - 15;
    int am = m < 0 ? -m : m, an = n < 0 ? -n : n;
    int lmin = am > an ? am : an;
    int nl = 16 - lmin;
    for (int li = 0; li < nl; ++li) {
        int l = lmin + li;
        int s = c_OFF[l] + (m + l)*(2*l + 1) + (n + l);
        zsh[li*256 + threadIdx.x] = zc[(size_t)s*256 + threadIdx.x];
        if (threadIdx.x < 32) wsh[li][threadIdx.x] = Wsy[(size_t)s*32 + threadIdx.x];
    }
    __syncthreads();
    float2 acc[32];
    #pragma unroll
    for (int j = 0; j < 32; ++j) acc[j] = make_float2(0.f, 0.f);
    for (int li = 0; li < nl; ++li) {
        float2 zv = zsh[li*256 + threadIdx.x];
        #pragma unroll
        for (int j = 0; j < 32; ++j) {
            float w = wsh[li][j];
            acc[j].x = fmaf(w, zv.x, acc[j].x);
            acc[j].y = fmaf(w, zv.y, acc[j].y);
        }
    }
    size_t base = ((size_t)mmi*32*31 + nni)*256 + threadIdx.x;
    #pragma unroll
    for (int j = 0; j < 32; ++j)
        Xc[base + (size_t)j*31*256] = acc[j];
}

// ---- U[j][bo][mm][g] = sum_n Xc[mm][j][nn][bo] e^{+2pi i n g/32} ----
__global__ void __launch_bounds__(256) k_u(const float2* Xc, float2* U) {
    __shared__ float2 Xsh[31*256];
    __shared__ float2 tw[32];
    int blk = blockIdx.x;              // mmi*32 + j
    int mmi = blk >> 5, j = blk & 31;
    const float2* xp = Xc + ((size_t)mmi*32 + j)*31*256;
    for (int t = threadIdx.x; t < 31*256; t += 256) Xsh[t] = xp[t];
    if (threadIdx.x < 32) {
        float sn, cs;
        sincosf(2.0f*PI_F*(float)threadIdx.x/32.0f, &sn, &cs);
        tw[threadIdx.x] = make_float2(cs, sn);   // e^{+2pi i t/32}
    }
    __syncthreads();
    float2 acc[32];
    #pragma unroll
    for (int g = 0; g < 32; ++g) acc[g] = make_float2(0.f, 0.f);
    for (int nni = 0; nni < 31; ++nni) {
        float2 xv = Xsh[nni*256 + threadIdx.x];
        int step = (nni + 17) & 31;    // (nni-15) mod 32, wave-uniform
        int t = 0;
        #pragma unroll
        for (int g = 0; g < 32; ++g) {
            float2 w = tw[t];
            acc[g].x += xv.x*w.x - xv.y*w.y;
            acc[g].y += xv.x*w.y + xv.y*w.x;
            t = (t + step) & 31;
        }
    }
    float2* up = U + (((size_t)j*256 + threadIdx.x)*31 + mmi)*32;
    #pragma unroll
    for (int g = 0; g < 32; ++g) up[g] = acc[g];
}

// ---- out[b][o][a][j][g] = bias[o] + sum_m Re(U[j][bo][mm][g] e^{+2pi i m a/32}) ----
__global__ void __launch_bounds__(256) k_out(const float2* U, const float* bias, float* out) {
    __shared__ float2 Ush[992];       // [mm][g]
    __shared__ float2 tw[32];
    int blk = blockIdx.x;             // bo*32 + j
    int bo = blk >> 5, j = blk & 31;
    const float2* up = U + ((size_t)j*256 + bo)*992;
    for (int t = threadIdx.x; t < 992; t += 256) Ush[t] = up[t];
    if (threadIdx.x < 32) {
        float sn, cs;
        sincosf(2.0f*PI_F*(float)threadIdx.x/32.0f, &sn, &cs);
        tw[threadIdx.x] = make_float2(cs, sn);
    }
    __syncthreads();
    float bv = bias[bo & 31];
    int a  = threadIdx.x >> 3;         // 0..31
    int g0 = (threadIdx.x & 7) << 2;   // 0,4,...,28
    float ac0 = bv, ac1 = bv, ac2 = bv, ac3 = bv;
    for (int mmi = 0; mmi < 31; ++mmi) {
        int t = (((mmi + 17) & 31) * a) & 31;  // (m*a) mod 32
        float2 w = tw[t];
        const float2* ur = Ush + mmi*32 + g0;
        float2 u0 = ur[0], u1 = ur[1], u2 = ur[2], u3 = ur[3];
        ac0 += u0.x*w.x - u0.y*w.y;
        ac1 += u1.x*w.x - u1.y*w.y;
        ac2 += u2.x*w.x - u2.y*w.y;
        ac3 += u3.x*w.x - u3.y*w.y;
    }
    float4 res = make_float4(ac0, ac1, ac2, ac3);
    *(float4*)(out + (((size_t)bo*32 + a)*32 + j)*32 + g0) = res;
}

extern "C" void kernel_launch(void* const* d_in, const int* in_sizes, int n_in,
                              void* d_out, int out_size, void* d_ws, size_t ws_size,
                              hipStream_t stream) {
    const float* x    = (const float*)d_in[0];  // (8,16,64,64,64)
    const float* kern = (const float*)d_in[1];  // (16,32,72)
    const float* bias = (const float*)d_in[2];  // (32,)
    const float* ge   = (const float*)d_in[3];  // (72,3)
    float* out = (float*)d_out;                 // (8,32,32,32,32)
    char* ws = (char*)d_ws;

    // workspace layout (bytes); U overlays dead regions after k_scatter
    float2* Xc  = (float2*)(ws);                  // 31*32*31*256 f2 = 62,980,096
    float*  Wan = (float*) (ws +  62980096);      // 5456*64  f32  =  1,396,736
    float*  Wsy = (float*) (ws +  64376832);      // 5456*32  f32  =    698,368
    float2* D   = (float2*)(ws +  65075200);      // 5456*72  f2   =  3,142,656
    float2* yc  = (float2*)(ws +  68217856);      // 5456*512 f2   = 22,347,776
    float2* zc  = (float2*)(ws +  90565632);      // 5456*256 f2   = 11,173,888
    float2* Fx  = (float2*)(ws + 101739520);      // 8192*496 f2   = 32,505,856
    float2* xc  = (float2*)(ws + 134245376);      // 5456*128 f2   =  5,586,944  (end 139,832,320)
    float2* U   = (float2*)(ws +  62980096);      // 8192*992 f2   = 65,011,712 (overlays Wan..zc, all dead)

    k_wigner_in  <<< 256, 256, 0, stream>>>(Wan);
    k_wigner_out <<< 128, 256, 0, stream>>>(Wsy);
    k_wigner_grid<<< 288, 256, 0, stream>>>(ge, D);
    k_yc         <<<5456, 256, 0, stream>>>(kern, D, yc);
    k_fft        <<<8192, 256, 0, stream>>>(x, Fx);
    k_xc         <<<3968, 256, 0, stream>>>(Fx, Wan, xc);   // 128 bf * 31 mm
    k_z          <<< 420, 256, 0, stream>>>(xc, yc, zc);
    k_scatter    <<< 961, 256, 0, stream>>>(zc, Wsy, Xc);   // 31*31
    k_u          <<< 992, 256, 0, stream>>>(Xc, U);         // 31*32
    k_out        <<<8192, 256, 0, stream>>>(U, bias, out);  // 256 bo * 32 j
}

// Round 3
// 669.912 us; speedup vs baseline: 1.5008x; 1.3086x over previous
//
#include <hip/hip_runtime.h>
#include <math.h>

#define PI_D 3.141592653589793238462643383279502884
#define PI_F 3.14159265358979323846f
#define SCALING_F (1.0f/12.0f)

// off[l] = sum_{j<l}(2j+1)^2
__constant__ int c_OFF[17] = {0,1,10,35,84,165,286,455,680,969,1330,1771,2300,2925,3654,4495,5456};
// cumulative blocks for k_z: per l: ceil(d/8)*d
__constant__ int c_Z8[17] = {0,1,4,9,16,34,56,82,112,163,220,283,352,452,560,676,800};

__device__ __forceinline__ void s_to_lmn(int s, int& l, int& m, int& n) {
    int ll = 15;
    while (s < c_OFF[ll]) --ll;
    int r = s - c_OFF[ll];
    int d = 2*ll + 1;
    l = ll;
    m = r / d - ll;
    n = r % d - ll;
}

// parallel table build: thread i (<64) fills entry i
__device__ __forceinline__ void build_tables_par(double beta, double* lf, double* cp, double* sp) {
    if (threadIdx.x < 64) {
        int i = threadIdx.x;
        lf[i] = lgamma((double)(i + 1));           // log(i!)
        double cb = cos(beta*0.5), sb = sin(beta*0.5);
        cp[i] = (i == 0) ? 1.0 : exp((double)i * log(cb));
        sp[i] = (i == 0) ? 1.0 : exp((double)i * log(sb));
    }
}

__device__ double wigner_d_dev(int l, int m, int n,
                               const double* lf, const double* cp, const double* sp) {
    int kmin = m - n; if (kmin < 0) kmin = 0;
    int kmax = l + m; { int k2 = l - n; if (k2 < kmax) kmax = k2; }
    double pref = 0.5*(lf[l+m] + lf[l-m] + lf[l+n] + lf[l-n]);
    double acc = 0.0;
    for (int k = kmin; k <= kmax; ++k) {
        double lg = pref - (lf[k] + lf[l+m-k] + lf[l-n-k] + lf[n-m+k]);
        double t = exp(lg) * cp[2*l + m - n - 2*k] * sp[n - m + 2*k];
        acc += (k & 1) ? -t : t;
    }
    return acc;
}

// ---- Wigner tables (transposed: W[j][s] for coalesced consumer reads) ----
__global__ void __launch_bounds__(256) k_wigner_in(float* WanT) {
    __shared__ double lf[64], cp[64], sp[64];
    __shared__ double tsum[32];
    __shared__ double wq;
    int j = blockIdx.x >> 2;        // 0..63
    int chunk = blockIdx.x & 3;
    double beta = PI_D * (2*j + 1) / 128.0;   // 4*B_IN = 128
    build_tables_par(beta, lf, cp, sp);
    if (threadIdx.x >= 64 && threadIdx.x < 96) {
        int k = threadIdx.x - 64;
        tsum[k] = sin((double)(2*j+1)*(2*k+1)*PI_D/128.0) / (double)(2*k+1);
    }
    __syncthreads();
    if (threadIdx.x == 0) {
        double inner = 0.0;
        for (int k = 0; k < 32; ++k) inner += tsum[k];
        wq = (2.0/32.0) * sin(PI_D*(2*j+1)/128.0) * inner / 4096.0; // /(2b)^2
    }
    __syncthreads();
    int s0 = chunk*1364, s1 = s0 + 1364; if (s1 > 5456) s1 = 5456;
    for (int s = s0 + threadIdx.x; s < s1; s += 256) {
        int l, m, n; s_to_lmn(s, l, m, n);
        WanT[j*5456 + s] = (float)(wigner_d_dev(l, m, n, lf, cp, sp) * wq);
    }
}

__global__ void __launch_bounds__(256) k_wigner_out(float* WsyT) {
    __shared__ double lf[64], cp[64], sp[64];
    int j = blockIdx.x >> 2;        // 0..31
    int chunk = blockIdx.x & 3;
    build_tables_par(PI_D*(2*j+1)/64.0, lf, cp, sp); // 4*B_OUT=64
    __syncthreads();
    int s0 = chunk*1364, s1 = s0 + 1364; if (s1 > 5456) s1 = 5456;
    for (int s = s0 + threadIdx.x; s < s1; s += 256) {
        int l, m, n; s_to_lmn(s, l, m, n);
        WsyT[j*5456 + s] = (float)(wigner_d_dev(l, m, n, lf, cp, sp) * (double)(2*l+1));
    }
}

__global__ void __launch_bounds__(256) k_wigner_grid(const float* ge, float2* D) {
    __shared__ double lf[64], cp[64], sp[64];
    int g = blockIdx.x >> 2;        // 0..71
    int chunk = blockIdx.x & 3;
    double beta = (double)ge[g*3 + 1];
    double alp  = (double)ge[g*3 + 0];
    double gam  = (double)ge[g*3 + 2];
    build_tables_par(beta, lf, cp, sp);
    __syncthreads();
    int s0 = chunk*1364, s1 = s0 + 1364; if (s1 > 5456) s1 = 5456;
    for (int s = s0 + threadIdx.x; s < s1; s += 256) {
        int l, m, n; s_to_lmn(s, l, m, n);
        double dv = wigner_d_dev(l, m, n, lf, cp, sp);
        double th = m*alp + n*gam;
        double sn, cs; sincos(th, &sn, &cs);
        D[s*72 + g] = make_float2((float)(dv*cs), (float)(-dv*sn));
    }
}

// ---- yc[s][io] = SCALING * sum_g kernel[io][g] * D[s][g]; 4 s per block ----
__global__ void __launch_bounds__(256) k_yc(const float* kern, const float2* D, float2* yc) {
    __shared__ float2 Ds[4][72];
    int s0 = blockIdx.x * 4;
    for (int t = threadIdx.x; t < 288; t += 256) {
        int ss = t / 72, g = t - ss*72;
        Ds[ss][g] = D[(size_t)(s0 + ss)*72 + g];
    }
    __syncthreads();
    for (int io = threadIdx.x; io < 512; io += 256) {
        const float* kp = kern + io*72;
        float2 a0 = {0,0}, a1 = {0,0}, a2 = {0,0}, a3 = {0,0};
        for (int g = 0; g < 72; ++g) {
            float kv = kp[g];
            a0.x = fmaf(kv, Ds[0][g].x, a0.x); a0.y = fmaf(kv, Ds[0][g].y, a0.y);
            a1.x = fmaf(kv, Ds[1][g].x, a1.x); a1.y = fmaf(kv, Ds[1][g].y, a1.y);
            a2.x = fmaf(kv, Ds[2][g].x, a2.x); a2.y = fmaf(kv, Ds[2][g].y, a2.y);
            a3.x = fmaf(kv, Ds[3][g].x, a3.x); a3.y = fmaf(kv, Ds[3][g].y, a3.y);
        }
        yc[(size_t)(s0+0)*512 + io] = make_float2(a0.x*SCALING_F, a0.y*SCALING_F);
        yc[(size_t)(s0+1)*512 + io] = make_float2(a1.x*SCALING_F, a1.y*SCALING_F);
        yc[(size_t)(s0+2)*512 + io] = make_float2(a2.x*SCALING_F, a2.y*SCALING_F);
        yc[(size_t)(s0+3)*512 + io] = make_float2(a3.x*SCALING_F, a3.y*SCALING_F);
    }
}

// ---- forward 2D partial DFT per (b,f,j): Fx[bf][j][mm 0..30][nn 0..15] ----
__global__ void __launch_bounds__(256) k_fft(const float* x, float2* Fx) {
    __shared__ float  xs[64][66];
    __shared__ float2 T1s[16][66];   // [nn][a]
    __shared__ float2 tw2[16][64];   // tw2[n][g] = e^{-2pi i n g/64}
    int blk = blockIdx.x;            // bf*64 + j
    int bf = blk >> 6, j = blk & 63;
    const float* xp = x + (size_t)bf*262144 + j*64;  // x[b,f,a,j,g]
    for (int t = threadIdx.x; t < 1024; t += 256) {
        int a = t >> 4, g4 = (t & 15) << 2;
        float4 v = *(const float4*)(xp + (size_t)a*4096 + g4);
        xs[a][g4] = v.x; xs[a][g4+1] = v.y; xs[a][g4+2] = v.z; xs[a][g4+3] = v.w;
    }
    for (int t = threadIdx.x; t < 1024; t += 256) {
        int n = t >> 6, g = t & 63;
        float sn, cs;
        sincosf(-2.0f*PI_F*(float)((n*g) & 63)/64.0f, &sn, &cs);
        tw2[n][g] = make_float2(cs, sn);
    }
    __syncthreads();
    // stage 1: T1[n][a] = sum_g x[a][g] tw2[n][g], n = 0..15
    {
        int ag = threadIdx.x & 31, ng = threadIdx.x >> 5;
        int a0 = ag*2, n0 = ng*2;
        float2 a00 = {0,0}, a01 = {0,0}, a10 = {0,0}, a11 = {0,0};
        for (int g0 = 0; g0 < 64; g0 += 4) {
            float  x0[4], x1[4]; float2 w0[4], w1[4];
            #pragma unroll
            for (int r = 0; r < 4; ++r) {
                x0[r] = xs[a0][g0+r];   x1[r] = xs[a0+1][g0+r];
                w0[r] = tw2[n0][g0+r];  w1[r] = tw2[n0+1][g0+r];
            }
            #pragma unroll
            for (int r = 0; r < 4; ++r) {
                a00.x = fmaf(x0[r], w0[r].x, a00.x); a00.y = fmaf(x0[r], w0[r].y, a00.y);
                a01.x = fmaf(x0[r], w1[r].x, a01.x); a01.y = fmaf(x0[r], w1[r].y, a01.y);
                a10.x = fmaf(x1[r], w0[r].x, a10.x); a10.y = fmaf(x1[r], w0[r].y, a10.y);
                a11.x = fmaf(x1[r], w1[r].x, a11.x); a11.y = fmaf(x1[r], w1[r].y, a11.y);
            }
        }
        T1s[n0  ][a0] = a00; T1s[n0+1][a0]   = a01;
        T1s[n0  ][a0+1] = a10; T1s[n0+1][a0+1] = a11;
    }
    __syncthreads();
    // stage 2: Fx[mm][nn] = sum_a T1[nn][a] e^{-2pi i (mm-15) a/64}
    {
        int nn = threadIdx.x & 15, mmg = threadIdx.x >> 4;
        int mm0 = mmg*2, mm1 = mm0 + 1;
        int am0 = mm0 >= 15 ? mm0 - 15 : 15 - mm0;
        int am1 = mm1 >= 15 ? mm1 - 15 : 15 - mm1;
        if (am1 > 15) am1 = 15;                 // pad slot mm=31, discarded
        float sg0 = mm0 >= 15 ? 1.f : -1.f;     // conj for negative m
        float sg1 = mm1 >= 15 ? 1.f : -1.f;
        float2 c0 = {0,0}, c1 = {0,0};
        for (int a0 = 0; a0 < 64; a0 += 4) {
            #pragma unroll
            for (int r = 0; r < 4; ++r) {
                float2 t1 = T1s[nn][a0+r];
                float2 wa = tw2[am0][a0+r];
                float2 wb = tw2[am1][a0+r];
                float way = wa.y*sg0, wby = wb.y*sg1;
                c0.x += t1.x*wa.x - t1.y*way;
                c0.y += t1.x*way + t1.y*wa.x;
                c1.x += t1.x*wb.x - t1.y*wby;
                c1.y += t1.x*wby + t1.y*wb.x;
            }
        }
        float2* outp = Fx + (size_t)blk*496;
        outp[mm0*16 + nn] = c0;
        if (mm1 < 31) outp[mm1*16 + nn] = c1;
    }
}

// ---- xc[s][bf] = sum_j WanT[j][s] * F(m(s),n(s)); block = (bf, mm) ----
__global__ void __launch_bounds__(256) k_xc(const float2* Fx, const float* WanT, float2* xc) {
    __shared__ float2 Fsh[31][65];   // [n+15][j]
    int blk = blockIdx.x;            // bf*31 + mm
    int bf = blk / 31, mm = blk - bf*31;
    int m = mm - 15;
    const float2* fp = Fx + (size_t)bf * 64 * 496;
    for (int t = threadIdx.x; t < 1024; t += 256) {   // n >= 0 from slice mm
        int j = t >> 4, nn = t & 15;
        Fsh[nn + 15][j] = fp[j*496 + mm*16 + nn];
    }
    for (int t = threadIdx.x; t < 1024; t += 256) {   // n < 0: conj of slice 30-mm
        int j = t >> 4, nn = t & 15;
        if (nn > 0) {
            float2 v = fp[j*496 + (30 - mm)*16 + nn];
            Fsh[15 - nn][j] = make_float2(v.x, -v.y);
        }
    }
    __syncthreads();
    int am = m < 0 ? -m : m;
    int q = threadIdx.x;
    int l = am;
    while (l <= 15 && q >= 2*l + 1) { q -= 2*l + 1; ++l; }
    if (l <= 15) {
        int n = q - l;
        int d = 2*l + 1;
        int s = c_OFF[l] + (m + l)*d + (n + l);
        const float* wp = WanT + s;
        const float2* frow = Fsh[n + 15];
        float ar = 0.f, ai = 0.f;
        for (int j2 = 0; j2 < 64; ++j2) {
            float w = wp[(size_t)j2*5456];
            ar = fmaf(w, frow[j2].x, ar);
            ai = fmaf(w, frow[j2].y, ai);
        }
        xc[(size_t)s*128 + bf] = make_float2(ar, ai);
    }
}

// ---- per-l complex GEMM: z[(m,b),(n,o)] = sum_{k,i} X[(m,b),(k,i)] Y[(k,i),(n,o)] ----
// block: M-tile 64 (8m x 8b), N-tile 32 (1n x 32o); double-buffered K-chunk = one k (16 i)
__global__ void __launch_bounds__(256) k_z(const float2* xc, const float2* yc, float2* zc) {
    __shared__ float2 Ash[2][16][66];   // [buf][i][mb], pad 66 (16B-aligned rows)
    __shared__ float2 Bsh[2][512];      // [buf][io]
    int blk = 799 - blockIdx.x;         // heavy l first
    int l = 0;
    while (l < 15 && blk >= c_Z8[l+1]) ++l;
    int r = blk - c_Z8[l];
    int d = 2*l + 1;
    int mt = r / d;
    int n0 = r - mt*d;
    int m0 = mt*8;
    int off = c_OFF[l];

    int tx = threadIdx.x & 15, ty = threadIdx.x >> 4;
    int o0 = tx*2;

    // staging indices: A: thread loads 4 consecutive float2 of one xc row
    int mloc_s = threadIdx.x >> 5;            // 0..7
    int bf0    = (threadIdx.x & 31) << 2;     // 0..124
    int bs     = bf0 >> 4;
    int i0s    = bf0 & 15;                    // 0,4,8,12
    int mrow_s = m0 + mloc_s; if (mrow_s > d-1) mrow_s = d-1;
    const float2* xrow = xc + (size_t)(off + mrow_s*d)*128 + bf0;   // k stride: +128
    // B: thread loads 2 consecutive float2 of the yc row (n0)
    int io0 = threadIdx.x * 2;
    const float2* yrow = yc + (size_t)(off + n0)*512 + io0;         // k stride: +d*512

    float4 apf0, apf1, bpf;
    apf0 = *(const float4*)(xrow);
    apf1 = *(const float4*)(xrow + 2);
    bpf  = *(const float4*)(yrow);
    Ash[0][i0s+0][mloc_s*8+bs] = make_float2(apf0.x, apf0.y);
    Ash[0][i0s+1][mloc_s*8+bs] = make_float2(apf0.z, apf0.w);
    Ash[0][i0s+2][mloc_s*8+bs] = make_float2(apf1.x, apf1.y);
    Ash[0][i0s+3][mloc_s*8+bs] = make_float2(apf1.z, apf1.w);
    *(float4*)&Bsh[0][io0] = bpf;
    __syncthreads();

    float2 acc[4][2];
    #pragma unroll
    for (int jm = 0; jm < 4; ++jm) { acc[jm][0] = make_float2(0.f,0.f); acc[jm][1] = make_float2(0.f,0.f); }

    for (int k = 0; k < d; ++k) {
        int cur = k & 1;
        if (k + 1 < d) {
            const float2* xr = xrow + (size_t)(k+1)*128;
            const float2* yr = yrow + (size_t)(k+1)*d*512;
            apf0 = *(const float4*)(xr);
            apf1 = *(const float4*)(xr + 2);
            bpf  = *(const float4*)(yr);
        }
        #pragma unroll
        for (int i = 0; i < 16; ++i) {
            const float4* ap = (const float4*)&Ash[cur][i][ty*4];
            float4 a01 = ap[0], a23 = ap[1];
            float4 b01 = *(const float4*)&Bsh[cur][i*32 + o0];
            float2 av[4] = {{a01.x,a01.y},{a01.z,a01.w},{a23.x,a23.y},{a23.z,a23.w}};
            float2 bv[2] = {{b01.x,b01.y},{b01.z,b01.w}};
            #pragma unroll
            for (int jm = 0; jm < 4; ++jm) {
                acc[jm][0].x += av[jm].x*bv[0].x - av[jm].y*bv[0].y;
                acc[jm][0].y += av[jm].x*bv[0].y + av[jm].y*bv[0].x;
                acc[jm][1].x += av[jm].x*bv[1].x - av[jm].y*bv[1].y;
                acc[jm][1].y += av[jm].x*bv[1].y + av[jm].y*bv[1].x;
            }
        }
        if (k + 1 < d) {
            int nxt = cur ^ 1;
            Ash[nxt][i0s+0][mloc_s*8+bs] = make_float2(apf0.x, apf0.y);
            Ash[nxt][i0s+1][mloc_s*8+bs] = make_float2(apf0.z, apf0.w);
            Ash[nxt][i0s+2][mloc_s*8+bs] = make_float2(apf1.x, apf1.y);
            Ash[nxt][i0s+3][mloc_s*8+bs] = make_float2(apf1.z, apf1.w);
            *(float4*)&Bsh[nxt][io0] = bpf;
            __syncthreads();
        }
    }
    #pragma unroll
    for (int jm = 0; jm < 4; ++jm) {
        int mb = ty*4 + jm;
        int mrow = m0 + (mb >> 3);
        int b = mb & 7;
        if (mrow < d) {
            size_t base = (size_t)(off + mrow*d + n0)*256 + b*32 + o0;
            zc[base]     = acc[jm][0];
            zc[base + 1] = acc[jm][1];
        }
    }
}

// ---- fused scatter + n-DFT:
// U[j][bo][mm][g] = sum_nn e^{+2pi i (nn-15) g/32} * (sum_l WsyT[j][s] * zc[s][bo]) ----
__global__ void __launch_bounds__(256) k_su(const float2* zc, const float* WsyT, float2* U) {
    __shared__ float wsh[496];      // [l*31 + nn]
    __shared__ float2 tw[32];
    int blk = blockIdx.x;           // mmi*32 + j
    int mmi = blk >> 5, j = blk & 31;
    int m = mmi - 15;
    int am = m < 0 ? -m : m;
    for (int t = threadIdx.x; t < 496; t += 256) {
        int l = t / 31, nn = t - l*31;
        int n = nn - 15, an = n < 0 ? -n : n;
        float w = 0.f;
        if (l >= am && l >= an) {
            int s = c_OFF[l] + (m + l)*(2*l + 1) + (n + l);
            w = WsyT[(size_t)j*5456 + s];
        }
        wsh[t] = w;
    }
    if (threadIdx.x < 32) {
        float sn, cs;
        sincosf(2.0f*PI_F*(float)threadIdx.x/32.0f, &sn, &cs);
        tw[threadIdx.x] = make_float2(cs, sn);
    }
    __syncthreads();
    float2 acc[32];
    #pragma unroll
    for (int g = 0; g < 32; ++g) acc[g] = make_float2(0.f, 0.f);
    for (int nni = 0; nni < 31; ++nni) {
        int n = nni - 15, an = n < 0 ? -n : n;
        int lmin = am > an ? am : an;
        float2 sv = make_float2(0.f, 0.f);
        for (int l = lmin; l < 16; ++l) {
            int s = c_OFF[l] + (m + l)*(2*l + 1) + (n + l);
            float2 zv = zc[(size_t)s*256 + threadIdx.x];
            float w = wsh[l*31 + nni];
            sv.x = fmaf(w, zv.x, sv.x);
            sv.y = fmaf(w, zv.y, sv.y);
        }
        int step = (nni + 17) & 31;    // (nni-15) mod 32
        int t = 0;
        #pragma unroll
        for (int g = 0; g < 32; ++g) {
            float2 w = tw[t];
            acc[g].x += sv.x*w.x - sv.y*w.y;
            acc[g].y += sv.x*w.y + sv.y*w.x;
            t = (t + step) & 31;
        }
    }
    float2* up = U + (((size_t)j*256 + threadIdx.x)*31 + mmi)*32;
    #pragma unroll
    for (int g = 0; g < 32; ++g) up[g] = acc[g];
}

// ---- out[b][o][a][j][g] = bias[o] + sum_m Re(U[j][bo][mm][g] e^{+2pi i m a/32}) ----
__global__ void __launch_bounds__(256) k_out(const float2* U, const float* bias, float* out) {
    __shared__ float2 Ush[992];       // [mm][g]
    __shared__ float2 tw[32];
    int blk = blockIdx.x;             // bo*32 + j
    int bo = blk >> 5, j = blk & 31;
    const float2* up = U + ((size_t)j*256 + bo)*992;
    for (int t = threadIdx.x; t < 992; t += 256) Ush[t] = up[t];
    if (threadIdx.x < 32) {
        float sn, cs;
        sincosf(2.0f*PI_F*(float)threadIdx.x/32.0f, &sn, &cs);
        tw[threadIdx.x] = make_float2(cs, sn);
    }
    __syncthreads();
    float bv = bias[bo & 31];
    int a  = threadIdx.x >> 3;         // 0..31
    int g0 = (threadIdx.x & 7) << 2;   // 0,4,...,28
    float ac0 = bv, ac1 = bv, ac2 = bv, ac3 = bv;
    for (int mmi = 0; mmi < 31; ++mmi) {
        int t = (((mmi + 17) & 31) * a) & 31;  // (m*a) mod 32
        float2 w = tw[t];
        const float2* ur = Ush + mmi*32 + g0;
        float2 u0 = ur[0], u1 = ur[1], u2 = ur[2], u3 = ur[3];
        ac0 += u0.x*w.x - u0.y*w.y;
        ac1 += u1.x*w.x - u1.y*w.y;
        ac2 += u2.x*w.x - u2.y*w.y;
        ac3 += u3.x*w.x - u3.y*w.y;
    }
    float4 res = make_float4(ac0, ac1, ac2, ac3);
    *(float4*)(out + (((size_t)bo*32 + a)*32 + j)*32 + g0) = res;
}

extern "C" void kernel_launch(void* const* d_in, const int* in_sizes, int n_in,
                              void* d_out, int out_size, void* d_ws, size_t ws_size,
                              hipStream_t stream) {
    const float* x    = (const float*)d_in[0];  // (8,16,64,64,64)
    const float* kern = (const float*)d_in[1];  // (16,32,72)
    const float* bias = (const float*)d_in[2];  // (32,)
    const float* ge   = (const float*)d_in[3];  // (72,3)
    float* out = (float*)d_out;                 // (8,32,32,32,32)
    char* ws = (char*)d_ws;

    // workspace layout (bytes). U (written by k_su) overlays WanT/D/yc/Fx/xc,
    // all of which are dead by then. Wsy and zc stay live outside U's region.
    float*  WsyT = (float*) (ws);                 // 32*5456 f32   =    698,368
    float2* zc   = (float2*)(ws +    698368);     // 5456*256 f2   = 11,173,888  (ends 11,872,256)
    float2* U    = (float2*)(ws +  11872256);     // 8192*992 f2   = 65,011,712  (ends 76,883,968)
    float*  WanT = (float*) (ws +  11872256);     // 64*5456 f32   =  1,396,736
    float2* D    = (float2*)(ws +  13268992);     // 5456*72  f2   =  3,142,656
    float2* yc   = (float2*)(ws +  16411648);     // 5456*512 f2   = 22,347,776
    float2* Fx   = (float2*)(ws +  38759424);     // 8192*496 f2   = 32,505,856
    float2* xc   = (float2*)(ws +  71265280);     // 5456*128 f2   =  5,586,944  (ends 76,852,224)

    k_wigner_in  <<< 256, 256, 0, stream>>>(WanT);
    k_wigner_out <<< 128, 256, 0, stream>>>(WsyT);
    k_wigner_grid<<< 288, 256, 0, stream>>>(ge, D);
    k_yc         <<<1364, 256, 0, stream>>>(kern, D, yc);
    k_fft        <<<8192, 256, 0, stream>>>(x, Fx);
    k_xc         <<<3968, 256, 0, stream>>>(Fx, WanT, xc);  // 128 bf * 31 mm
    k_z          <<< 800, 256, 0, stream>>>(xc, yc, zc);
    k_su         <<< 992, 256, 0, stream>>>(zc, WsyT, U);   // 31 mm * 32 j
    k_out        <<<8192, 256, 0, stream>>>(U, bias, out);  // 256 bo * 32 j
}

// Round 4
// 635.191 us; speedup vs baseline: 1.5828x; 1.0547x over previous
//
#include <hip/hip_runtime.h>
#include <math.h>

#define PI_D 3.141592653589793238462643383279502884
#define PI_F 3.14159265358979323846f
#define SCALING_F (1.0f/12.0f)

// off[l] = sum_{j<l}(2j+1)^2
__constant__ int c_OFF[17] = {0,1,10,35,84,165,286,455,680,969,1330,1771,2300,2925,3654,4495,5456};
// cumulative blocks for k_z: per l: ceil(d/8)*d
__constant__ int c_Z8[17] = {0,1,4,9,16,34,56,82,112,163,220,283,352,452,560,676,800};

__device__ __forceinline__ void s_to_lmn(int s, int& l, int& m, int& n) {
    int ll = 15;
    while (s < c_OFF[ll]) --ll;
    int r = s - c_OFF[ll];
    int d = 2*ll + 1;
    l = ll;
    m = r / d - ll;
    n = r % d - ll;
}

// parallel table build: thread i (<64) fills entry i
__device__ __forceinline__ void build_tables_par(double beta, double* lf, double* cp, double* sp) {
    if (threadIdx.x < 64) {
        int i = threadIdx.x;
        lf[i] = lgamma((double)(i + 1));           // log(i!)
        double cb = cos(beta*0.5), sb = sin(beta*0.5);
        cp[i] = (i == 0) ? 1.0 : exp((double)i * log(cb));
        sp[i] = (i == 0) ? 1.0 : exp((double)i * log(sb));
    }
}

__device__ double wigner_d_dev(int l, int m, int n,
                               const double* lf, const double* cp, const double* sp) {
    int kmin = m - n; if (kmin < 0) kmin = 0;
    int kmax = l + m; { int k2 = l - n; if (k2 < kmax) kmax = k2; }
    double pref = 0.5*(lf[l+m] + lf[l-m] + lf[l+n] + lf[l-n]);
    double acc = 0.0;
    for (int k = kmin; k <= kmax; ++k) {
        double lg = pref - (lf[k] + lf[l+m-k] + lf[l-n-k] + lf[n-m+k]);
        double t = exp(lg) * cp[2*l + m - n - 2*k] * sp[n - m + 2*k];
        acc += (k & 1) ? -t : t;
    }
    return acc;
}

// ---- Wigner tables (transposed: W[j][s] for coalesced consumer reads) ----
__global__ void __launch_bounds__(256) k_wigner_in(float* WanT) {
    __shared__ double lf[64], cp[64], sp[64];
    __shared__ double tsum[32];
    __shared__ double wq;
    int j = blockIdx.x >> 2;        // 0..63
    int chunk = blockIdx.x & 3;
    double beta = PI_D * (2*j + 1) / 128.0;   // 4*B_IN = 128
    build_tables_par(beta, lf, cp, sp);
    if (threadIdx.x >= 64 && threadIdx.x < 96) {
        int k = threadIdx.x - 64;
        tsum[k] = sin((double)(2*j+1)*(2*k+1)*PI_D/128.0) / (double)(2*k+1);
    }
    __syncthreads();
    if (threadIdx.x == 0) {
        double inner = 0.0;
        for (int k = 0; k < 32; ++k) inner += tsum[k];
        wq = (2.0/32.0) * sin(PI_D*(2*j+1)/128.0) * inner / 4096.0; // /(2b)^2
    }
    __syncthreads();
    int s0 = chunk*1364, s1 = s0 + 1364; if (s1 > 5456) s1 = 5456;
    for (int s = s0 + threadIdx.x; s < s1; s += 256) {
        int l, m, n; s_to_lmn(s, l, m, n);
        WanT[j*5456 + s] = (float)(wigner_d_dev(l, m, n, lf, cp, sp) * wq);
    }
}

__global__ void __launch_bounds__(256) k_wigner_out(float* WsyT) {
    __shared__ double lf[64], cp[64], sp[64];
    int j = blockIdx.x >> 2;        // 0..31
    int chunk = blockIdx.x & 3;
    build_tables_par(PI_D*(2*j+1)/64.0, lf, cp, sp); // 4*B_OUT=64
    __syncthreads();
    int s0 = chunk*1364, s1 = s0 + 1364; if (s1 > 5456) s1 = 5456;
    for (int s = s0 + threadIdx.x; s < s1; s += 256) {
        int l, m, n; s_to_lmn(s, l, m, n);
        WsyT[j*5456 + s] = (float)(wigner_d_dev(l, m, n, lf, cp, sp) * (double)(2*l+1));
    }
}

__global__ void __launch_bounds__(256) k_wigner_grid(const float* ge, float2* D) {
    __shared__ double lf[64], cp[64], sp[64];
    int g = blockIdx.x >> 2;        // 0..71
    int chunk = blockIdx.x & 3;
    double beta = (double)ge[g*3 + 1];
    double alp  = (double)ge[g*3 + 0];
    double gam  = (double)ge[g*3 + 2];
    build_tables_par(beta, lf, cp, sp);
    __syncthreads();
    int s0 = chunk*1364, s1 = s0 + 1364; if (s1 > 5456) s1 = 5456;
    for (int s = s0 + threadIdx.x; s < s1; s += 256) {
        int l, m, n; s_to_lmn(s, l, m, n);
        double dv = wigner_d_dev(l, m, n, lf, cp, sp);
        double th = m*alp + n*gam;
        double sn, cs; sincos(th, &sn, &cs);
        D[s*72 + g] = make_float2((float)(dv*cs), (float)(-dv*sn));
    }
}

// ---- yc[s][io] = SCALING * sum_g kernel[io][g] * D[s][g]; 4 s per block ----
__global__ void __launch_bounds__(256) k_yc(const float* kern, const float2* D, float2* yc) {
    __shared__ float2 Ds[4][72];
    int s0 = blockIdx.x * 4;
    for (int t = threadIdx.x; t < 288; t += 256) {
        int ss = t / 72, g = t - ss*72;
        Ds[ss][g] = D[(size_t)(s0 + ss)*72 + g];
    }
    __syncthreads();
    for (int io = threadIdx.x; io < 512; io += 256) {
        const float* kp = kern + io*72;
        float2 a0 = {0,0}, a1 = {0,0}, a2 = {0,0}, a3 = {0,0};
        for (int g = 0; g < 72; ++g) {
            float kv = kp[g];
            a0.x = fmaf(kv, Ds[0][g].x, a0.x); a0.y = fmaf(kv, Ds[0][g].y, a0.y);
            a1.x = fmaf(kv, Ds[1][g].x, a1.x); a1.y = fmaf(kv, Ds[1][g].y, a1.y);
            a2.x = fmaf(kv, Ds[2][g].x, a2.x); a2.y = fmaf(kv, Ds[2][g].y, a2.y);
            a3.x = fmaf(kv, Ds[3][g].x, a3.x); a3.y = fmaf(kv, Ds[3][g].y, a3.y);
        }
        yc[(size_t)(s0+0)*512 + io] = make_float2(a0.x*SCALING_F, a0.y*SCALING_F);
        yc[(size_t)(s0+1)*512 + io] = make_float2(a1.x*SCALING_F, a1.y*SCALING_F);
        yc[(size_t)(s0+2)*512 + io] = make_float2(a2.x*SCALING_F, a2.y*SCALING_F);
        yc[(size_t)(s0+3)*512 + io] = make_float2(a3.x*SCALING_F, a3.y*SCALING_F);
    }
}

// ---- forward 2D partial DFT per (b,f,j): Fx[bf][j][mm 0..30][nn 0..15] ----
// v3: conflict-free LDS layouts (stride 66 == 2 mod 32 -> 2-way, free),
// wave-uniform broadcast twiddles, b64/b128 vector LDS ops.
__global__ void __launch_bounds__(256) k_fft(const float* x, float2* Fx) {
    __shared__ float  xs[64][66];    // pad 66: 2-way banks, 8B-aligned rows
    __shared__ float2 T1s[16][66];   // [nn][a], pad 66: 16B-aligned, distinct banks
    __shared__ float2 tw2[16][66];   // tw2[n][g]=e^{-2pi i n g/64}; pad 66
    int blk = blockIdx.x;            // bf*64 + j
    int bf = blk >> 6, j = blk & 63;
    const float* xp = x + (size_t)bf*262144 + j*64;  // x[b,f,a,j,g]
    for (int t = threadIdx.x; t < 1024; t += 256) {
        int a = t >> 4, g4 = (t & 15) << 2;
        float4 v = *(const float4*)(xp + (size_t)a*4096 + g4);
        *(float2*)&xs[a][g4]     = make_float2(v.x, v.y);
        *(float2*)&xs[a][g4 + 2] = make_float2(v.z, v.w);
    }
    for (int t = threadIdx.x; t < 1024; t += 256) {
        int n = t >> 6, g = t & 63;
        float sn, cs;
        sincosf(-2.0f*PI_F*(float)((n*g) & 63)/64.0f, &sn, &cs);
        tw2[n][g] = make_float2(cs, sn);
    }
    __syncthreads();
    // stage 1: T1[n][a] = sum_g x[a][g] tw2[n][g]; thread = (a, n0..n0+3), n0 wave-uniform
    {
        int a  = threadIdx.x & 63;
        int n0 = (threadIdx.x >> 6) << 2;
        float2 c0 = {0,0}, c1 = {0,0}, c2 = {0,0}, c3 = {0,0};
        for (int g = 0; g < 64; g += 2) {
            float2 xv = *(const float2*)&xs[a][g];            // 2-way banks: free
            float4 w0 = *(const float4*)&tw2[n0    ][g];      // broadcast
            float4 w1 = *(const float4*)&tw2[n0 + 1][g];
            float4 w2 = *(const float4*)&tw2[n0 + 2][g];
            float4 w3 = *(const float4*)&tw2[n0 + 3][g];
            c0.x = fmaf(xv.x, w0.x, c0.x); c0.y = fmaf(xv.x, w0.y, c0.y);
            c0.x = fmaf(xv.y, w0.z, c0.x); c0.y = fmaf(xv.y, w0.w, c0.y);
            c1.x = fmaf(xv.x, w1.x, c1.x); c1.y = fmaf(xv.x, w1.y, c1.y);
            c1.x = fmaf(xv.y, w1.z, c1.x); c1.y = fmaf(xv.y, w1.w, c1.y);
            c2.x = fmaf(xv.x, w2.x, c2.x); c2.y = fmaf(xv.x, w2.y, c2.y);
            c2.x = fmaf(xv.y, w2.z, c2.x); c2.y = fmaf(xv.y, w2.w, c2.y);
            c3.x = fmaf(xv.x, w3.x, c3.x); c3.y = fmaf(xv.x, w3.y, c3.y);
            c3.x = fmaf(xv.y, w3.z, c3.x); c3.y = fmaf(xv.y, w3.w, c3.y);
        }
        T1s[n0    ][a] = c0;
        T1s[n0 + 1][a] = c1;
        T1s[n0 + 2][a] = c2;
        T1s[n0 + 3][a] = c3;
    }
    __syncthreads();
    // stage 2: Fx[mm][nn] = sum_a T1[nn][a] e^{-2pi i (mm-15) a/64}; thread = (nn, 2mm)
    {
        int nn = threadIdx.x & 15, mmg = threadIdx.x >> 4;
        int mm0 = mmg*2, mm1 = mm0 + 1;
        int am0 = mm0 >= 15 ? mm0 - 15 : 15 - mm0;
        int am1 = mm1 >= 15 ? mm1 - 15 : 15 - mm1;
        if (am1 > 15) am1 = 15;                 // pad slot mm=31, discarded
        float sg0 = mm0 >= 15 ? 1.f : -1.f;     // conj for negative m
        float sg1 = mm1 >= 15 ? 1.f : -1.f;
        float2 c0 = {0,0}, c1 = {0,0};
        for (int a = 0; a < 64; a += 2) {
            float4 t01 = *(const float4*)&T1s[nn][a];     // T1[a], T1[a+1]
            float4 wa  = *(const float4*)&tw2[am0][a];    // rows 8..15: distinct bank groups
            float4 wb  = *(const float4*)&tw2[am1][a];
            float way0 = wa.y*sg0, way1 = wa.w*sg0;
            float wby0 = wb.y*sg1, wby1 = wb.w*sg1;
            c0.x += t01.x*wa.x - t01.y*way0;
            c0.y += t01.x*way0 + t01.y*wa.x;
            c0.x += t01.z*wa.z - t01.w*way1;
            c0.y += t01.z*way1 + t01.w*wa.z;
            c1.x += t01.x*wb.x - t01.y*wby0;
            c1.y += t01.x*wby0 + t01.y*wb.x;
            c1.x += t01.z*wb.z - t01.w*wby1;
            c1.y += t01.z*wby1 + t01.w*wb.z;
        }
        float2* outp = Fx + (size_t)blk*496;
        outp[mm0*16 + nn] = c0;
        if (mm1 < 31) outp[mm1*16 + nn] = c1;
    }
}

// ---- xc[s][bf] = sum_j WanT[j][s] * F(m(s),n(s)); block = (bf, mm) ----
__global__ void __launch_bounds__(256) k_xc(const float2* Fx, const float* WanT, float2* xc) {
    __shared__ float2 Fsh[31][65];   // [n+15][j]
    int blk = blockIdx.x;            // bf*31 + mm
    int bf = blk / 31, mm = blk - bf*31;
    int m = mm - 15;
    const float2* fp = Fx + (size_t)bf * 64 * 496;
    for (int t = threadIdx.x; t < 1024; t += 256) {   // n >= 0 from slice mm
        int j = t >> 4, nn = t & 15;
        Fsh[nn + 15][j] = fp[j*496 + mm*16 + nn];
    }
    for (int t = threadIdx.x; t < 1024; t += 256) {   // n < 0: conj of slice 30-mm
        int j = t >> 4, nn = t & 15;
        if (nn > 0) {
            float2 v = fp[j*496 + (30 - mm)*16 + nn];
            Fsh[15 - nn][j] = make_float2(v.x, -v.y);
        }
    }
    __syncthreads();
    int am = m < 0 ? -m : m;
    int q = threadIdx.x;
    int l = am;
    while (l <= 15 && q >= 2*l + 1) { q -= 2*l + 1; ++l; }
    if (l <= 15) {
        int n = q - l;
        int d = 2*l + 1;
        int s = c_OFF[l] + (m + l)*d + (n + l);
        const float* wp = WanT + s;
        const float2* frow = Fsh[n + 15];
        float ar = 0.f, ai = 0.f;
        for (int j2 = 0; j2 < 64; ++j2) {
            float w = wp[(size_t)j2*5456];
            ar = fmaf(w, frow[j2].x, ar);
            ai = fmaf(w, frow[j2].y, ai);
        }
        xc[(size_t)s*128 + bf] = make_float2(ar, ai);
    }
}

// ---- per-l complex GEMM: z[(m,b),(n,o)] = sum_{k,i} X[(m,b),(k,i)] Y[(k,i),(n,o)] ----
__global__ void __launch_bounds__(256) k_z(const float2* xc, const float2* yc, float2* zc) {
    __shared__ float2 Ash[2][16][66];   // [buf][i][mb]
    __shared__ float2 Bsh[2][512];      // [buf][io]
    int blk = 799 - blockIdx.x;         // heavy l first
    int l = 0;
    while (l < 15 && blk >= c_Z8[l+1]) ++l;
    int r = blk - c_Z8[l];
    int d = 2*l + 1;
    int mt = r / d;
    int n0 = r - mt*d;
    int m0 = mt*8;
    int off = c_OFF[l];

    int tx = threadIdx.x & 15, ty = threadIdx.x >> 4;
    int o0 = tx*2;

    int mloc_s = threadIdx.x >> 5;            // 0..7
    int bf0    = (threadIdx.x & 31) << 2;     // 0..124
    int bs     = bf0 >> 4;
    int i0s    = bf0 & 15;                    // 0,4,8,12
    int mrow_s = m0 + mloc_s; if (mrow_s > d-1) mrow_s = d-1;
    const float2* xrow = xc + (size_t)(off + mrow_s*d)*128 + bf0;   // k stride: +128
    int io0 = threadIdx.x * 2;
    const float2* yrow = yc + (size_t)(off + n0)*512 + io0;         // k stride: +d*512

    float4 apf0, apf1, bpf;
    apf0 = *(const float4*)(xrow);
    apf1 = *(const float4*)(xrow + 2);
    bpf  = *(const float4*)(yrow);
    Ash[0][i0s+0][mloc_s*8+bs] = make_float2(apf0.x, apf0.y);
    Ash[0][i0s+1][mloc_s*8+bs] = make_float2(apf0.z, apf0.w);
    Ash[0][i0s+2][mloc_s*8+bs] = make_float2(apf1.x, apf1.y);
    Ash[0][i0s+3][mloc_s*8+bs] = make_float2(apf1.z, apf1.w);
    *(float4*)&Bsh[0][io0] = bpf;
    __syncthreads();

    float2 acc[4][2];
    #pragma unroll
    for (int jm = 0; jm < 4; ++jm) { acc[jm][0] = make_float2(0.f,0.f); acc[jm][1] = make_float2(0.f,0.f); }

    for (int k = 0; k < d; ++k) {
        int cur = k & 1;
        if (k + 1 < d) {
            const float2* xr = xrow + (size_t)(k+1)*128;
            const float2* yr = yrow + (size_t)(k+1)*d*512;
            apf0 = *(const float4*)(xr);
            apf1 = *(const float4*)(xr + 2);
            bpf  = *(const float4*)(yr);
        }
        #pragma unroll
        for (int i = 0; i < 16; ++i) {
            const float4* ap = (const float4*)&Ash[cur][i][ty*4];
            float4 a01 = ap[0], a23 = ap[1];
            float4 b01 = *(const float4*)&Bsh[cur][i*32 + o0];
            float2 av[4] = {{a01.x,a01.y},{a01.z,a01.w},{a23.x,a23.y},{a23.z,a23.w}};
            float2 bv[2] = {{b01.x,b01.y},{b01.z,b01.w}};
            #pragma unroll
            for (int jm = 0; jm < 4; ++jm) {
                acc[jm][0].x += av[jm].x*bv[0].x - av[jm].y*bv[0].y;
                acc[jm][0].y += av[jm].x*bv[0].y + av[jm].y*bv[0].x;
                acc[jm][1].x += av[jm].x*bv[1].x - av[jm].y*bv[1].y;
                acc[jm][1].y += av[jm].x*bv[1].y + av[jm].y*bv[1].x;
            }
        }
        if (k + 1 < d) {
            int nxt = cur ^ 1;
            Ash[nxt][i0s+0][mloc_s*8+bs] = make_float2(apf0.x, apf0.y);
            Ash[nxt][i0s+1][mloc_s*8+bs] = make_float2(apf0.z, apf0.w);
            Ash[nxt][i0s+2][mloc_s*8+bs] = make_float2(apf1.x, apf1.y);
            Ash[nxt][i0s+3][mloc_s*8+bs] = make_float2(apf1.z, apf1.w);
            *(float4*)&Bsh[nxt][io0] = bpf;
            __syncthreads();
        }
    }
    #pragma unroll
    for (int jm = 0; jm < 4; ++jm) {
        int mb = ty*4 + jm;
        int mrow = m0 + (mb >> 3);
        int b = mb & 7;
        if (mrow < d) {
            size_t base = (size_t)(off + mrow*d + n0)*256 + b*32 + o0;
            zc[base]     = acc[jm][0];
            zc[base + 1] = acc[jm][1];
        }
    }
}

// ---- fused scatter + n-DFT ----
__global__ void __launch_bounds__(256) k_su(const float2* zc, const float* WsyT, float2* U) {
    __shared__ float wsh[496];      // [l*31 + nn]
    __shared__ float2 tw[32];
    int blk = blockIdx.x;           // mmi*32 + j
    int mmi = blk >> 5, j = blk & 31;
    int m = mmi - 15;
    int am = m < 0 ? -m : m;
    for (int t = threadIdx.x; t < 496; t += 256) {
        int l = t / 31, nn = t - l*31;
        int n = nn - 15, an = n < 0 ? -n : n;
        float w = 0.f;
        if (l >= am && l >= an) {
            int s = c_OFF[l] + (m + l)*(2*l + 1) + (n + l);
            w = WsyT[(size_t)j*5456 + s];
        }
        wsh[t] = w;
    }
    if (threadIdx.x < 32) {
        float sn, cs;
        sincosf(2.0f*PI_F*(float)threadIdx.x/32.0f, &sn, &cs);
        tw[threadIdx.x] = make_float2(cs, sn);
    }
    __syncthreads();
    float2 acc[32];
    #pragma unroll
    for (int g = 0; g < 32; ++g) acc[g] = make_float2(0.f, 0.f);
    for (int nni = 0; nni < 31; ++nni) {
        int n = nni - 15, an = n < 0 ? -n : n;
        int lmin = am > an ? am : an;
        float2 sv = make_float2(0.f, 0.f);
        for (int l = lmin; l < 16; ++l) {
            int s = c_OFF[l] + (m + l)*(2*l + 1) + (n + l);
            float2 zv = zc[(size_t)s*256 + threadIdx.x];
            float w = wsh[l*31 + nni];
            sv.x = fmaf(w, zv.x, sv.x);
            sv.y = fmaf(w, zv.y, sv.y);
        }
        int step = (nni + 17) & 31;    // (nni-15) mod 32
        int t = 0;
        #pragma unroll
        for (int g = 0; g < 32; ++g) {
            float2 w = tw[t];
            acc[g].x += sv.x*w.x - sv.y*w.y;
            acc[g].y += sv.x*w.y + sv.y*w.x;
            t = (t + step) & 31;
        }
    }
    float2* up = U + (((size_t)j*256 + threadIdx.x)*31 + mmi)*32;
    #pragma unroll
    for (int g = 0; g < 32; ++g) up[g] = acc[g];
}

// ---- out[b][o][a][j][g] = bias[o] + sum_m Re(U[j][bo][mm][g] e^{+2pi i m a/32}) ----
__global__ void __launch_bounds__(256) k_out(const float2* U, const float* bias, float* out) {
    __shared__ float2 Ush[992];       // [mm][g]
    __shared__ float2 tw[32];
    int blk = blockIdx.x;             // bo*32 + j
    int bo = blk >> 5, j = blk & 31;
    const float2* up = U + ((size_t)j*256 + bo)*992;
    for (int t = threadIdx.x; t < 992; t += 256) Ush[t] = up[t];
    if (threadIdx.x < 32) {
        float sn, cs;
        sincosf(2.0f*PI_F*(float)threadIdx.x/32.0f, &sn, &cs);
        tw[threadIdx.x] = make_float2(cs, sn);
    }
    __syncthreads();
    float bv = bias[bo & 31];
    int a  = threadIdx.x >> 3;         // 0..31
    int g0 = (threadIdx.x & 7) << 2;   // 0,4,...,28
    float ac0 = bv, ac1 = bv, ac2 = bv, ac3 = bv;
    for (int mmi = 0; mmi < 31; ++mmi) {
        int t = (((mmi + 17) & 31) * a) & 31;  // (m*a) mod 32
        float2 w = tw[t];
        const float2* ur = Ush + mmi*32 + g0;
        float2 u0 = ur[0], u1 = ur[1], u2 = ur[2], u3 = ur[3];
        ac0 += u0.x*w.x - u0.y*w.y;
        ac1 += u1.x*w.x - u1.y*w.y;
        ac2 += u2.x*w.x - u2.y*w.y;
        ac3 += u3.x*w.x - u3.y*w.y;
    }
    float4 res = make_float4(ac0, ac1, ac2, ac3);
    *(float4*)(out + (((size_t)bo*32 + a)*32 + j)*32 + g0) = res;
}

extern "C" void kernel_launch(void* const* d_in, const int* in_sizes, int n_in,
                              void* d_out, int out_size, void* d_ws, size_t ws_size,
                              hipStream_t stream) {
    const float* x    = (const float*)d_in[0];  // (8,16,64,64,64)
    const float* kern = (const float*)d_in[1];  // (16,32,72)
    const float* bias = (const float*)d_in[2];  // (32,)
    const float* ge   = (const float*)d_in[3];  // (72,3)
    float* out = (float*)d_out;                 // (8,32,32,32,32)
    char* ws = (char*)d_ws;

    float*  WsyT = (float*) (ws);                 // 32*5456 f32   =    698,368
    float2* zc   = (float2*)(ws +    698368);     // 5456*256 f2   = 11,173,888
    float2* U    = (float2*)(ws +  11872256);     // 8192*992 f2   = 65,011,712
    float*  WanT = (float*) (ws +  11872256);     // 64*5456 f32   =  1,396,736
    float2* D    = (float2*)(ws +  13268992);     // 5456*72  f2   =  3,142,656
    float2* yc   = (float2*)(ws +  16411648);     // 5456*512 f2   = 22,347,776
    float2* Fx   = (float2*)(ws +  38759424);     // 8192*496 f2   = 32,505,856
    float2* xc   = (float2*)(ws +  71265280);     // 5456*128 f2   =  5,586,944

    k_wigner_in  <<< 256, 256, 0, stream>>>(WanT);
    k_wigner_out <<< 128, 256, 0, stream>>>(WsyT);
    k_wigner_grid<<< 288, 256, 0, stream>>>(ge, D);
    k_yc         <<<1364, 256, 0, stream>>>(kern, D, yc);
    k_fft        <<<8192, 256, 0, stream>>>(x, Fx);
    k_xc         <<<3968, 256, 0, stream>>>(Fx, WanT, xc);  // 128 bf * 31 mm
    k_z          <<< 800, 256, 0, stream>>>(xc, yc, zc);
    k_su         <<< 992, 256, 0, stream>>>(zc, WsyT, U);   // 31 mm * 32 j
    k_out        <<<8192, 256, 0, stream>>>(U, bias, out);  // 256 bo * 32 j
}